// Round 9
// baseline (523.651 us; speedup 1.0000x reference)
//
#include <hip/hip_runtime.h>
#include <math.h>

#define BATCH 32
#define HH 1024
#define WW 1024
#define WR 513
#define NPIX (HH * WR)
#define TWO_PI_F 6.28318530717958647692f

// Same-wave LDS fence (each wave touches only its own LDS region).
#define LGKM_SYNC() __asm__ __volatile__("s_waitcnt lgkmcnt(0)" ::: "memory")

// pu staging index: pad +8 floats per 256 to spread the 4x 256-aligned
// lane groups across banks (4-way -> ~2-way).
#define PUIDX(h) ((h) + (((h) >> 8) << 3))

__device__ __forceinline__ float2 cadd(float2 a, float2 b) { return make_float2(a.x + b.x, a.y + b.y); }
__device__ __forceinline__ float2 csub(float2 a, float2 b) { return make_float2(a.x - b.x, a.y - b.y); }
__device__ __forceinline__ float2 cmul(float2 a, float2 b) {
    return make_float2(a.x * b.x - a.y * b.y, a.x * b.y + a.y * b.x);
}

// atan2 via odd minimax poly on [0,1] (max err ~1e-5 rad) + quadrant fixup.
__device__ __forceinline__ float fast_atan2f(float y, float x) {
    float ax = __builtin_fabsf(x), ay = __builtin_fabsf(y);
    float mx = fmaxf(ax, ay), mn = fminf(ax, ay);
    float a = mn * __builtin_amdgcn_rcpf(mx);
    float s = a * a;
    float r = fmaf(fmaf(fmaf(fmaf(0.0208351f, s, -0.085133f), s, 0.180141f),
                        s, -0.3302995f), s, 0.999866f) * a;
    if (ay > ax) r = 1.5707963268f - r;
    if (x < 0.0f) r = 3.1415926536f - r;
    return (y < 0.0f) ? -r : r;
}

// Natural-order 16-point FFT, in place, fully in registers.
__device__ __forceinline__ void fft16(float2* d) {
    float2 b[16];
#pragma unroll
    for (int t = 0; t < 4; ++t) {
        float2 x0 = d[t], x1 = d[t + 4], x2 = d[t + 8], x3 = d[t + 12];
        float2 a0 = cadd(x0, x2), a1 = csub(x0, x2), a2 = cadd(x1, x3), a3 = csub(x1, x3);
        b[4 * t + 0] = cadd(a0, a2);
        b[4 * t + 1] = make_float2(a1.x + a3.y, a1.y - a3.x);
        b[4 * t + 2] = csub(a0, a2);
        b[4 * t + 3] = make_float2(a1.x - a3.y, a1.y + a3.x);
    }
    const float2 W1[4] = {make_float2(1.0f, 0.0f),
                          make_float2(0.92387953f, -0.38268343f),
                          make_float2(0.70710678f, -0.70710678f),
                          make_float2(0.38268343f, -0.92387953f)};
#pragma unroll
    for (int t = 0; t < 4; ++t) {
        float2 w1 = W1[t], w2 = cmul(w1, w1), w3 = cmul(w2, w1);
        float2 x0 = b[t], x1 = cmul(b[t + 4], w1), x2 = cmul(b[t + 8], w2), x3 = cmul(b[t + 12], w3);
        float2 a0 = cadd(x0, x2), a1 = csub(x0, x2), a2 = cadd(x1, x3), a3 = csub(x1, x3);
        d[t + 0]  = cadd(a0, a2);
        d[t + 4]  = make_float2(a1.x + a3.y, a1.y - a3.x);
        d[t + 8]  = csub(a0, a2);
        d[t + 12] = make_float2(a1.x - a3.y, a1.y + a3.x);
    }
}

// Wave-level 1024-pt FFT. Input: v[j] = x[lane + 64*j]. sb = this wave's
// PRIVATE 1088-float LDS scratch. No block barriers.
// Output: v[m] = X[(lane&15) + 16*m + 256*kq], kq = 2*((lane>>4)&1) + ((lane>>5)&1).
__device__ __forceinline__ void wave_fft1024(float2* v, float* sb, int lane) {
    fft16(v);
    float s, c;
    __sincosf(-TWO_PI_F * (float)lane * (1.0f / 1024.0f), &s, &c);
    float2 T = make_float2(c, s), w = T;
#pragma unroll
    for (int k2 = 1; k2 < 16; ++k2) { v[k2] = cmul(v[k2], w); w = cmul(w, T); }
    const int k2p = lane & 15, qp = lane >> 4;
    float tx[16];
#pragma unroll
    for (int k2 = 0; k2 < 16; ++k2) sb[68 * k2 + lane] = v[k2].x;
    LGKM_SYNC();
#pragma unroll
    for (int m = 0; m < 16; ++m) tx[m] = sb[68 * k2p + 4 * m + qp];
    LGKM_SYNC();
#pragma unroll
    for (int k2 = 0; k2 < 16; ++k2) sb[68 * k2 + lane] = v[k2].y;
    LGKM_SYNC();
#pragma unroll
    for (int m = 0; m < 16; ++m) v[m] = make_float2(tx[m], sb[68 * k2p + 4 * m + qp]);
    LGKM_SYNC();
    fft16(v);
    __sincosf(-TWO_PI_F * (float)qp * (1.0f / 64.0f), &s, &c);
    float2 U = make_float2(c, s);
    w = U;
#pragma unroll
    for (int km = 1; km < 16; ++km) { v[km] = cmul(v[km], w); w = cmul(w, U); }
    const bool hi2 = (lane & 32) != 0, hi1 = (lane & 16) != 0;
#pragma unroll
    for (int m = 0; m < 16; ++m) {
        float2 a = v[m];
        float2 o = make_float2(__shfl_xor(a.x, 32, 64), __shfl_xor(a.y, 32, 64));
        float2 s1 = hi2 ? csub(o, a) : cadd(a, o);
        if (hi2 && hi1) s1 = make_float2(s1.y, -s1.x);
        float2 o2 = make_float2(__shfl_xor(s1.x, 16, 64), __shfl_xor(s1.y, 16, 64));
        v[m] = hi1 ? csub(o2, s1) : cadd(s1, o2);
    }
}

// ---------------------------------------------------------------------------
// Kernel A: 4 waves/block, each wave = 2 packed real rows -> 1 complex FFT.
// ---------------------------------------------------------------------------
__global__ __launch_bounds__(256, 4) void row_fft_kernel(const float* __restrict__ x,
                                                         float2* __restrict__ rf2) {
    __shared__ float2 buf[4 * 1088];
    const int t = threadIdx.x, w = t >> 6, lane = t & 63;
    const int b = blockIdx.x >> 7;
    const int h0 = (blockIdx.x & 127) * 8;
    const float* r0 = x + ((long long)b * HH + h0 + 2 * w) * (long long)WW;
    const float* r1 = r0 + WW;
    float2 v[16];
#pragma unroll
    for (int j = 0; j < 16; ++j) v[j] = make_float2(r0[lane + 64 * j], r1[lane + 64 * j]);
    float2* mybuf = buf + w * 1088;
    wave_fft1024(v, (float*)mybuf, lane);
    const int kq = 2 * ((lane >> 4) & 1) + ((lane >> 5) & 1);
    const int kbase = (lane & 15) + 256 * kq;
#pragma unroll
    for (int m = 0; m < 16; ++m) mybuf[kbase + 16 * m] = v[m];
    __syncthreads();
    for (int idx = t; idx < 513 * 8; idx += 256) {
        int k = idx >> 3, j = idx & 7, p = j >> 1, which = j & 1;
        float2 zk = buf[p * 1088 + k];
        float2 zn = buf[p * 1088 + ((1024 - k) & 1023)];
        float2 val = which ? make_float2(0.5f * (zk.y + zn.y), 0.5f * (zn.x - zk.x))
                           : make_float2(0.5f * (zk.x + zn.x), 0.5f * (zk.y - zn.y));
        rf2[((long long)b * WR + k) * 1024 + h0 + j] = val;
    }
}

// ---------------------------------------------------------------------------
// Kernel B: FUSED column FFT + phase + magnitude + Zernike moments + gy
// stats + mask count. 2 waves/block, each wave owns one (b,k) row entirely.
// Per-wave 58-float partial goes to the dead upper half of its own row:
// floats 1024..1081. Global pu (floats 0..1023) still written for gx_kernel.
// Partial layout j: 0..29 cos-moments, 30..54 sin-moments, 55 sgy, 56 sgy2, 57 cnt.
// ---------------------------------------------------------------------------
__global__ __launch_bounds__(128, 4) void col_fft_kernel(float2* __restrict__ rf2,
                                                         float* __restrict__ magmax) {
    __shared__ float sb[2 * 1088];
    const int t = threadIdx.x, w = t >> 6, lane = t & 63;
    const int fid = blockIdx.x * 2 + w;
    const int b = fid / WR, k = fid - b * WR;
    float2* row = rf2 + ((long long)b * WR + k) * 1024;
    float2 v[16];
#pragma unroll
    for (int j = 0; j < 16; ++j) v[j] = row[lane + 64 * j];
    float* mysb = sb + w * 1088;
    wave_fft1024(v, mysb, lane);

    float* pu = (float*)row;
    const int kq = 2 * ((lane >> 4) & 1) + ((lane >> 5) & 1);
    const int hbase = (lane & 15) + 256 * kq;
    float mmax = 0.0f;
#pragma unroll
    for (int m = 0; m < 16; ++m) {
        float2 z = v[m];
        mmax = fmaxf(mmax, __builtin_amdgcn_sqrtf(z.x * z.x + z.y * z.y));
        float ph = fast_atan2f(z.y, z.x);
        float p = (ph < 0.0f) ? ph + TWO_PI_F : ph;
        const int h = hbase + 16 * m;
        pu[h] = p;                 // global (for gx_kernel)
        mysb[PUIDX(h)] = p;        // LDS (for gy + moments)
    }
#pragma unroll
    for (int off = 32; off; off >>= 1) mmax = fmaxf(mmax, __shfl_down(mmax, off));
    if (lane == 0) atomicMax((int*)(magmax + b), __float_as_int(mmax));
    LGKM_SYNC();

    // ---- fused per-row stats: gy + 55 moments + cnt ----
    const float xv = -1.0f + (1.0f / 256.0f) * (float)k;
    const float xv2 = xv * xv;
    float a00 = 0.f, a11 = 0.f, a20 = 0.f, a22 = 0.f, a31 = 0.f, a33 = 0.f,
          a40 = 0.f, a42 = 0.f, a44 = 0.f, a51 = 0.f, a53 = 0.f, a55 = 0.f,
          a60 = 0.f, a62 = 0.f, a64 = 0.f, a66 = 0.f, a71 = 0.f, a73 = 0.f,
          a75 = 0.f, a77 = 0.f, a80 = 0.f, a82 = 0.f, a84 = 0.f, a86 = 0.f,
          a88 = 0.f, a91 = 0.f, a93 = 0.f, a95 = 0.f, a97 = 0.f, a99 = 0.f;
    float b11 = 0.f, b22 = 0.f, b31 = 0.f, b33 = 0.f, b42 = 0.f, b44 = 0.f,
          b51 = 0.f, b53 = 0.f, b55 = 0.f, b62 = 0.f, b64 = 0.f, b66 = 0.f,
          b71 = 0.f, b73 = 0.f, b75 = 0.f, b77 = 0.f, b82 = 0.f, b84 = 0.f,
          b86 = 0.f, b88 = 0.f, b91 = 0.f, b93 = 0.f, b95 = 0.f, b97 = 0.f,
          b99 = 0.f;
    float sgy = 0.f, sgy2 = 0.f, cnt = 0.f;

#pragma unroll
    for (int m = 0; m < 16; ++m) {
        const int h = hbase + 16 * m;
        const float v0 = mysb[PUIDX(h)];
        float gy;
        if (h == 0)         gy = mysb[PUIDX(1)] - v0;
        else if (h == 1023) gy = v0 - mysb[PUIDX(1022)];
        else                gy = 0.5f * (mysb[PUIDX(h + 1)] - mysb[PUIDX(h - 1)]);
        sgy += gy; sgy2 += gy * gy;

        const float yv = -1.0f + (2.0f / 1023.0f) * (float)h;
        const float r2 = xv2 + yv * yv;
        if (r2 <= 1.0f) {
            cnt += 1.0f;
            const float rho = sqrtf(r2);
            const float inv = rsqrtf(r2);
            const float c1 = xv * inv;
            const float s1 = yv * inv;
            const float c2 = 2.f * c1 * c1 - 1.f;
            const float c3 = 2.f * c1 * c2 - c1;
            const float c4 = 2.f * c1 * c3 - c2;
            const float c5 = 2.f * c1 * c4 - c3;
            const float c6 = 2.f * c1 * c5 - c4;
            const float c7 = 2.f * c1 * c6 - c5;
            const float c8 = 2.f * c1 * c7 - c6;
            const float c9 = 2.f * c1 * c8 - c7;
            const float s2 = 2.f * c1 * s1;
            const float s3 = 2.f * c1 * s2 - s1;
            const float s4 = 2.f * c1 * s3 - s2;
            const float s5 = 2.f * c1 * s4 - s3;
            const float s6 = 2.f * c1 * s5 - s4;
            const float s7 = 2.f * c1 * s6 - s5;
            const float s8 = 2.f * c1 * s7 - s6;
            const float s9 = 2.f * c1 * s8 - s7;
            const float w0 = v0,       w1 = w0 * rho, w2 = w1 * rho, w3 = w2 * rho,
                        w4 = w3 * rho, w5 = w4 * rho, w6 = w5 * rho, w7 = w6 * rho,
                        w8 = w7 * rho, w9 = w8 * rho;
            a00 += w0;
            a11 += w1 * c1;
            a20 += w2;      a22 += w2 * c2;
            a31 += w3 * c1; a33 += w3 * c3;
            a40 += w4;      a42 += w4 * c2; a44 += w4 * c4;
            a51 += w5 * c1; a53 += w5 * c3; a55 += w5 * c5;
            a60 += w6;      a62 += w6 * c2; a64 += w6 * c4; a66 += w6 * c6;
            a71 += w7 * c1; a73 += w7 * c3; a75 += w7 * c5; a77 += w7 * c7;
            a80 += w8;      a82 += w8 * c2; a84 += w8 * c4; a86 += w8 * c6; a88 += w8 * c8;
            a91 += w9 * c1; a93 += w9 * c3; a95 += w9 * c5; a97 += w9 * c7; a99 += w9 * c9;
            b11 += w1 * s1;
            b22 += w2 * s2;
            b31 += w3 * s1; b33 += w3 * s3;
            b42 += w4 * s2; b44 += w4 * s4;
            b51 += w5 * s1; b53 += w5 * s3; b55 += w5 * s5;
            b62 += w6 * s2; b64 += w6 * s4; b66 += w6 * s6;
            b71 += w7 * s1; b73 += w7 * s3; b75 += w7 * s5; b77 += w7 * s7;
            b82 += w8 * s2; b84 += w8 * s4; b86 += w8 * s6; b88 += w8 * s8;
            b91 += w9 * s1; b93 += w9 * s3; b95 += w9 * s5; b97 += w9 * s7; b99 += w9 * s9;
        }
    }
    LGKM_SYNC();   // all lanes done reading pu from LDS before reduction reuse

    // wave-reduce 58 accumulators -> LDS slots -> coalesced partial store
#define CWRED(var, idx)                                                     \
    {                                                                       \
        float r_ = var;                                                     \
        _Pragma("unroll")                                                   \
        for (int off_ = 32; off_; off_ >>= 1) r_ += __shfl_down(r_, off_);  \
        if (lane == 0) mysb[(idx)] = r_;                                    \
    }
    CWRED(a00, 0);  CWRED(a11, 1);  CWRED(a20, 2);  CWRED(a22, 3);  CWRED(a31, 4);
    CWRED(a33, 5);  CWRED(a40, 6);  CWRED(a42, 7);  CWRED(a44, 8);  CWRED(a51, 9);
    CWRED(a53, 10); CWRED(a55, 11); CWRED(a60, 12); CWRED(a62, 13); CWRED(a64, 14);
    CWRED(a66, 15); CWRED(a71, 16); CWRED(a73, 17); CWRED(a75, 18); CWRED(a77, 19);
    CWRED(a80, 20); CWRED(a82, 21); CWRED(a84, 22); CWRED(a86, 23); CWRED(a88, 24);
    CWRED(a91, 25); CWRED(a93, 26); CWRED(a95, 27); CWRED(a97, 28); CWRED(a99, 29);
    CWRED(b11, 30); CWRED(b22, 31); CWRED(b31, 32); CWRED(b33, 33); CWRED(b42, 34);
    CWRED(b44, 35); CWRED(b51, 36); CWRED(b53, 37); CWRED(b55, 38); CWRED(b62, 39);
    CWRED(b64, 40); CWRED(b66, 41); CWRED(b71, 42); CWRED(b73, 43); CWRED(b75, 44);
    CWRED(b77, 45); CWRED(b82, 46); CWRED(b84, 47); CWRED(b86, 48); CWRED(b88, 49);
    CWRED(b91, 50); CWRED(b93, 51); CWRED(b95, 52); CWRED(b97, 53); CWRED(b99, 54);
    CWRED(sgy, 55); CWRED(sgy2, 56); CWRED(cnt, 57);
#undef CWRED
    LGKM_SYNC();
    if (lane < 58) pu[1024 + lane] = mysb[lane];
}

// ---------------------------------------------------------------------------
// Kernel C: gx gradient stats only (needs neighbor k-rows). float4 loads.
// Block = (9 k-rows) x batch; partial {sgx, sgx2} -> floats 1100,1101 of
// row (b, k0) upper half.
// ---------------------------------------------------------------------------
__global__ __launch_bounds__(256, 2) void gx_kernel(float* __restrict__ pu) {
    __shared__ float red[2 * 4];
    const int b = blockIdx.y;
    const int k0 = blockIdx.x * 9;
    float* base = pu + (long long)b * WR * 2048;
    const int t = threadIdx.x;
    float sgx = 0.f, sgx2 = 0.f;
    for (int kk = 0; kk < 9; ++kk) {
        const int k = k0 + kk;
        const float* rowc = base + (long long)k * 2048;
        float4 g4;
        if (k == 0) {
            float4 c4 = *(const float4*)(rowc + 4 * t);
            float4 p4 = *(const float4*)(rowc + 2048 + 4 * t);
            g4 = make_float4(p4.x - c4.x, p4.y - c4.y, p4.z - c4.z, p4.w - c4.w);
        } else if (k == WR - 1) {
            float4 c4 = *(const float4*)(rowc + 4 * t);
            float4 m4 = *(const float4*)(rowc - 2048 + 4 * t);
            g4 = make_float4(c4.x - m4.x, c4.y - m4.y, c4.z - m4.z, c4.w - m4.w);
        } else {
            float4 p4 = *(const float4*)(rowc + 2048 + 4 * t);
            float4 m4 = *(const float4*)(rowc - 2048 + 4 * t);
            g4 = make_float4(0.5f * (p4.x - m4.x), 0.5f * (p4.y - m4.y),
                             0.5f * (p4.z - m4.z), 0.5f * (p4.w - m4.w));
        }
        sgx += g4.x + g4.y + g4.z + g4.w;
        sgx2 += g4.x * g4.x + g4.y * g4.y + g4.z * g4.z + g4.w * g4.w;
    }
    const int wv = t >> 6, lane = t & 63;
#pragma unroll
    for (int off = 32; off; off >>= 1) sgx += __shfl_down(sgx, off);
#pragma unroll
    for (int off = 32; off; off >>= 1) sgx2 += __shfl_down(sgx2, off);
    if (lane == 0) { red[wv] = sgx; red[4 + wv] = sgx2; }
    __syncthreads();
    if (t == 0) {
        float* dst = base + (long long)k0 * 2048 + 1100;
        dst[0] = red[0] + red[1] + red[2] + red[3];
        dst[1] = red[4] + red[5] + red[6] + red[7];
    }
}

// ---------------------------------------------------------------------------
// Kernel D: sum partials per batch, map moments -> Zernike coeffs, finalize.
// ---------------------------------------------------------------------------
__device__ int moment_index(int p, int a, int is_cos) {
    int ai = 0;
    for (int pp = 0; pp < 10; ++pp)
        for (int aa = (pp & 1); aa <= pp; aa += 2) {
            if (is_cos && pp == p && aa == a) return ai;
            ++ai;
        }
    for (int pp = 1; pp < 10; ++pp)
        for (int aa = ((pp & 1) ? 1 : 2); aa <= pp; aa += 2) {
            if (!is_cos && pp == p && aa == a) return ai;
            ++ai;
        }
    return 0;
}

__device__ float factf(int n) {
    float f = 1.0f;
    for (int i = 2; i <= n; ++i) f *= (float)i;
    return f;
}

__global__ void finalize_kernel(const float* __restrict__ pu,
                                const float* __restrict__ magmax,
                                float* __restrict__ out) {
    __shared__ float abf[64];
    const int b = blockIdx.x;
    const int j = threadIdx.x;
    const float* base = pu + (long long)b * WR * 2048;
    if (j < 58) {                       // per-(b,k) fused partials
        float s = 0.0f;
        for (int i = 0; i < WR; ++i)
            s += base[(long long)i * 2048 + 1024 + j];
        abf[j] = s;
    } else if (j == 58) {               // gx partials: sum
        float s = 0.0f;
        for (int i = 0; i < 57; ++i)
            s += base[(long long)(i * 9) * 2048 + 1100];
        abf[58] = s;
    } else if (j == 59) {               // gx partials: sum of squares
        float s = 0.0f;
        for (int i = 0; i < 57; ++i)
            s += base[(long long)(i * 9) * 2048 + 1101];
        abf[59] = s;
    }
    __syncthreads();
    if (j >= 60) return;
    const float NF = (float)NPIX;
    float val;
    if (j < 55) {
        int tt = j, n = 0;
        while (tt >= n + 1) { tt -= (n + 1); ++n; }
        int m = -n + 2 * tt;
        int am = m < 0 ? -m : m;
        float s = 0.0f;
        for (int k = 0; k <= (n - am) / 2; ++k) {
            float c = factf(n - k) /
                      (factf(k) * factf((n + am) / 2 - k) * factf((n - am) / 2 - k));
            if (k & 1) c = -c;
            int p = n - 2 * k;
            s += c * abf[moment_index(p, am, m >= 0 ? 1 : 0)];
        }
        val = s / abf[57];
    } else if (j == 55) {               // gx mean
        val = abf[58] / NF;
    } else if (j == 56) {               // gy mean
        val = abf[55] / NF;
    } else if (j == 57) {               // gx std (ddof=1)
        float sum = abf[58], sq = abf[59];
        val = sqrtf(fmaxf(0.0f, (sq - sum * sum / NF) / (NF - 1.0f)));
    } else if (j == 58) {               // gy std (ddof=1)
        float sum = abf[55], sq = abf[56];
        val = sqrtf(fmaxf(0.0f, (sq - sum * sum / NF) / (NF - 1.0f)));
    } else {
        val = magmax[b];
    }
    out[b * 60 + j] = val;
}

// ---------------------------------------------------------------------------
extern "C" void kernel_launch(void* const* d_in, const int* in_sizes, int n_in,
                              void* d_out, int out_size, void* d_ws, size_t ws_size,
                              hipStream_t stream) {
    (void)in_sizes; (void)n_in; (void)out_size; (void)ws_size;
    const float* x = (const float*)d_in[0];
    float* out = (float*)d_out;

    float* magmax = (float*)d_ws;                  // 32 floats (atomicMax target)
    float2* rf2 = (float2*)((char*)d_ws + 16384);  // [B][WR][H] float2 = 134.5 MB

    (void)hipMemsetAsync(d_ws, 0, 16384, stream);
    row_fft_kernel<<<BATCH * 128, 256, 0, stream>>>(x, rf2);
    col_fft_kernel<<<(BATCH * WR) / 2, 128, 0, stream>>>(rf2, magmax);
    dim3 gridG(57, BATCH);
    gx_kernel<<<gridG, 256, 0, stream>>>((float*)rf2);
    finalize_kernel<<<BATCH, 64, 0, stream>>>((const float*)rf2, magmax, out);
}